// Round 1
// baseline (680.178 us; speedup 1.0000x reference)
//
#include <hip/hip_runtime.h>

#define NN 50000
#define EE 800000
#define RR 8
#define DD 128
#define SS (NN*RR)      // 400000 segments
#define TE (2*EE)       // 1600000 symmetrized edges

typedef __attribute__((ext_vector_type(8))) short bf16x8;
typedef __attribute__((ext_vector_type(4))) float f32x4;

__device__ __forceinline__ unsigned short f2bf(float f){
  unsigned int u = __float_as_uint(f);
  u += 0x7fffu + ((u >> 16) & 1u);   // round-to-nearest-even
  return (unsigned short)(u >> 16);
}
__device__ __forceinline__ float bf2f(unsigned short h){
  return __uint_as_float(((unsigned int)h) << 16);
}

// ---- prep: x fp32 -> bf16 -------------------------------------------------
__global__ void k_conv_x(const float* __restrict__ x, unsigned short* __restrict__ xb){
  int i = blockIdx.x*blockDim.x + threadIdx.x;
  if (i >= NN*DD/4) return;
  float4 v = ((const float4*)x)[i];
  ushort4 o;
  o.x = f2bf(v.x); o.y = f2bf(v.y); o.z = f2bf(v.z); o.w = f2bf(v.w);
  ((ushort4*)xb)[i] = o;
}

// ---- prep: W[r][k][n] fp32 -> wb[r][n][k] bf16 (B-fragment layout), r=8 is self_weight
__global__ void k_conv_w(const float* __restrict__ w, const float* __restrict__ sw,
                         unsigned short* __restrict__ wb){
  int i = blockIdx.x*blockDim.x + threadIdx.x;
  if (i >= 9*DD*DD) return;
  int r = i >> 14; int rem = i & 16383; int n = rem >> 7; int k = rem & 127;
  float v = (r < 8) ? w[r*16384 + k*128 + n] : sw[k*128 + n];
  wb[i] = f2bf(v);
}

// ---- CSR build ------------------------------------------------------------
__global__ void k_count(const int* __restrict__ ei, const int* __restrict__ et,
                        int* __restrict__ counts){
  int e = blockIdx.x*blockDim.x + threadIdx.x;
  if (e >= EE) return;
  int s = ei[e], d = ei[EE + e], t = et[e];
  atomicAdd(&counts[d*RR + t], 1);
  atomicAdd(&counts[s*RR + t], 1);
}

__global__ void k_scan1(const int* __restrict__ counts, int* __restrict__ offs,
                        int* __restrict__ blksum){
  __shared__ int sd[256];
  int b = blockIdx.x, tid = threadIdx.x;
  int base = b*1024 + tid*4;
  int v0 = (base+0 < SS) ? counts[base+0] : 0;
  int v1 = (base+1 < SS) ? counts[base+1] : 0;
  int v2 = (base+2 < SS) ? counts[base+2] : 0;
  int v3 = (base+3 < SS) ? counts[base+3] : 0;
  int ts = v0+v1+v2+v3;
  sd[tid] = ts; __syncthreads();
  for (int o = 1; o < 256; o <<= 1){
    int t = (tid >= o) ? sd[tid-o] : 0;
    __syncthreads();
    sd[tid] += t;
    __syncthreads();
  }
  int ex = sd[tid] - ts;
  if (base+0 < SS) offs[base+0] = ex; ex += v0;
  if (base+1 < SS) offs[base+1] = ex; ex += v1;
  if (base+2 < SS) offs[base+2] = ex; ex += v2;
  if (base+3 < SS) offs[base+3] = ex;
  if (tid == 255) blksum[b] = sd[255];
}

__global__ void k_scan2(int* __restrict__ blksum, int* __restrict__ offs, int nb){
  __shared__ int sd[512];
  int tid = threadIdx.x;
  int v = (tid < nb) ? blksum[tid] : 0;
  sd[tid] = v; __syncthreads();
  for (int o = 1; o < 512; o <<= 1){
    int t = (tid >= o) ? sd[tid-o] : 0;
    __syncthreads();
    sd[tid] += t;
    __syncthreads();
  }
  if (tid < nb) blksum[tid] = sd[tid] - v;   // exclusive
  if (tid == 0) offs[SS] = TE;
}

__global__ void k_scan3(int* __restrict__ offs, const int* __restrict__ blksum,
                        int* __restrict__ cursor){
  int i = blockIdx.x*blockDim.x + threadIdx.x;
  if (i >= SS) return;
  int v = offs[i] + blksum[i >> 10];
  offs[i] = v;
  cursor[i] = v;
}

__global__ void k_scatter(const int* __restrict__ ei, const int* __restrict__ et,
                          int* __restrict__ cursor, int* __restrict__ esrc){
  int e = blockIdx.x*blockDim.x + threadIdx.x;
  if (e >= EE) return;
  int s = ei[e], d = ei[EE + e], t = et[e];
  int p = atomicAdd(&cursor[d*RR + t], 1); esrc[p] = s;
  int q = atomicAdd(&cursor[s*RR + t], 1); esrc[q] = d;
}

// ---- fused gather + degree-scale + GEMM -----------------------------------
// block = 256 (4 waves); tile = 64 dst rows x 128 out cols.
// wave w gathers rows [w*16, w*16+16), computes out cols [w*32, w*32+32).
__global__ __launch_bounds__(256) void k_fused(
    const unsigned short* __restrict__ xb,
    const unsigned short* __restrict__ wb,
    const int* __restrict__ offs,
    const int* __restrict__ esrc,
    float* __restrict__ out)
{
  __shared__ __align__(16) unsigned short Alds[64][136];  // +8 bf16 pad -> 2-way bank alias (free)
  int tid  = threadIdx.x;
  int wave = tid >> 6, lane = tid & 63;
  int l15  = lane & 15, quad = lane >> 4;
  int rowbase = blockIdx.x * 64;

  f32x4 C[4][2];
  #pragma unroll
  for (int m = 0; m < 4; ++m){ C[m][0] = (f32x4)(0.f); C[m][1] = (f32x4)(0.f); }

  for (int rr = 0; rr < 9; ++rr){
    // B fragments for this wave's 32 output cols (straight from global/L2):
    // frag[j] = W_rr[k = ks*32 + quad*8 + j][n = wave*32 + nt*16 + l15]
    const unsigned short* wr = wb + rr * 16384;
    bf16x8 bfrag[2][4];
    #pragma unroll
    for (int nt = 0; nt < 2; ++nt)
      #pragma unroll
      for (int ks = 0; ks < 4; ++ks)
        bfrag[nt][ks] = *(const bf16x8*)(wr + (wave*32 + nt*16 + l15)*128 + ks*32 + quad*8);

    // gather: wave fills rows [wave*16, wave*16+16) of A tile
    #pragma unroll 1
    for (int d = 0; d < 16; ++d){
      int rowl = wave*16 + d;
      int gd = rowbase + rowl;
      float a0 = 0.f, a1 = 0.f;
      if (gd < NN){
        if (rr < 8){
          int s0  = gd*RR + rr;
          int off = offs[s0];
          int cnt = offs[s0+1] - off;
          for (int e = 0; e < cnt; ++e){
            int src = esrc[off + e];
            unsigned int v = *(const unsigned int*)(xb + src*DD + lane*2);
            a0 += bf2f((unsigned short)(v & 0xffffu));
            a1 += bf2f((unsigned short)(v >> 16));
          }
          float sc = (cnt > 0) ? (1.0f / (float)cnt) : 0.f;
          a0 *= sc; a1 *= sc;
        } else {
          // self-loop pseudo-relation: A row = x_bf16[gd], scale 1
          unsigned int v = *(const unsigned int*)(xb + gd*DD + lane*2);
          a0 = bf2f((unsigned short)(v & 0xffffu));
          a1 = bf2f((unsigned short)(v >> 16));
        }
      }
      unsigned int pk = ((unsigned int)f2bf(a1) << 16) | (unsigned int)f2bf(a0);
      *(unsigned int*)&Alds[rowl][lane*2] = pk;
    }
    __syncthreads();

    #pragma unroll
    for (int m = 0; m < 4; ++m){
      #pragma unroll
      for (int ks = 0; ks < 4; ++ks){
        bf16x8 af = *(const bf16x8*)&Alds[m*16 + l15][ks*32 + quad*8];
        C[m][0] = __builtin_amdgcn_mfma_f32_16x16x32_bf16(af, bfrag[0][ks], C[m][0], 0, 0, 0);
        C[m][1] = __builtin_amdgcn_mfma_f32_16x16x32_bf16(af, bfrag[1][ks], C[m][1], 0, 0, 0);
      }
    }
    __syncthreads();
  }

  // epilogue: C/D layout col = lane&15, row = quad*4 + reg
  #pragma unroll
  for (int m = 0; m < 4; ++m){
    #pragma unroll
    for (int nt = 0; nt < 2; ++nt){
      #pragma unroll
      for (int i = 0; i < 4; ++i){
        int row = m*16 + quad*4 + i;
        int gd  = rowbase + row;
        int col = wave*32 + nt*16 + l15;
        if (gd < NN) out[gd*DD + col] = C[m][nt][i];
      }
    }
  }
}

// ---- workspace layout (bytes) ---------------------------------------------
// counts   @ 0          : SS*4        = 1,600,000
// offs     @ 1,600,000  : (SS+1)*4    = 1,600,004 (+pad)
// cursor   @ 3,200,016  : SS*4        = 1,600,000
// blksum   @ 4,800,016  : 512*4       = 2,048
// esrc     @ 4,802,064  : TE*4        = 6,400,000
// xb       @ 11,202,064 : NN*DD*2     = 12,800,000
// wb       @ 24,002,064 : 9*DD*DD*2   = 294,912
// total ~ 24.30 MB
extern "C" void kernel_launch(void* const* d_in, const int* in_sizes, int n_in,
                              void* d_out, int out_size, void* d_ws, size_t ws_size,
                              hipStream_t stream){
  const float* x  = (const float*)d_in[0];
  const float* w  = (const float*)d_in[1];
  const float* sw = (const float*)d_in[2];
  const int*   ei = (const int*)d_in[3];
  const int*   et = (const int*)d_in[4];
  float* out = (float*)d_out;
  char* ws = (char*)d_ws;

  if (ws_size < (size_t)24300000) return;  // constant per-call; fails loudly via validation

  int* counts = (int*)(ws + 0);
  int* offs   = (int*)(ws + 1600000);
  int* cursor = (int*)(ws + 3200016);
  int* blksum = (int*)(ws + 4800016);
  int* esrc   = (int*)(ws + 4802064);
  unsigned short* xb = (unsigned short*)(ws + 11202064);
  unsigned short* wb = (unsigned short*)(ws + 24002064);

  hipMemsetAsync(counts, 0, SS*sizeof(int), stream);
  k_conv_x <<<(NN*DD/4 + 255)/256, 256, 0, stream>>>(x, xb);
  k_conv_w <<<(9*DD*DD + 255)/256, 256, 0, stream>>>(w, sw, wb);
  k_count  <<<(EE + 255)/256,      256, 0, stream>>>(ei, et, counts);
  k_scan1  <<<391,                 256, 0, stream>>>(counts, offs, blksum);
  k_scan2  <<<1,                   512, 0, stream>>>(blksum, offs, 391);
  k_scan3  <<<(SS + 255)/256,      256, 0, stream>>>(offs, blksum, cursor);
  k_scatter<<<(EE + 255)/256,      256, 0, stream>>>(ei, et, cursor, esrc);
  k_fused  <<<(NN + 63)/64,        256, 0, stream>>>(xb, wb, offs, esrc, out);
}

// Round 2
// 578.642 us; speedup vs baseline: 1.1755x; 1.1755x over previous
//
#include <hip/hip_runtime.h>

#define NN 50000
#define EE 800000
#define RR 8
#define DD 128
#define SS (NN*RR)      // 400000 segments
#define TE (2*EE)       // 1600000 symmetrized edges

typedef __attribute__((ext_vector_type(8))) short bf16x8;
typedef __attribute__((ext_vector_type(4))) float f32x4;

__device__ __forceinline__ unsigned short f2bf(float f){
  unsigned int u = __float_as_uint(f);
  u += 0x7fffu + ((u >> 16) & 1u);   // round-to-nearest-even
  return (unsigned short)(u >> 16);
}
__device__ __forceinline__ float bf2f(unsigned short h){
  return __uint_as_float(((unsigned int)h) << 16);
}

// ---- prep: x fp32 -> bf16 -------------------------------------------------
__global__ void k_conv_x(const float* __restrict__ x, unsigned short* __restrict__ xb){
  int i = blockIdx.x*blockDim.x + threadIdx.x;
  if (i >= NN*DD/4) return;
  float4 v = ((const float4*)x)[i];
  ushort4 o;
  o.x = f2bf(v.x); o.y = f2bf(v.y); o.z = f2bf(v.z); o.w = f2bf(v.w);
  ((ushort4*)xb)[i] = o;
}

// ---- prep: W[r][k][n] fp32 -> wb[r][n][k] bf16 (B-fragment layout), r=8 is self_weight
__global__ void k_conv_w(const float* __restrict__ w, const float* __restrict__ sw,
                         unsigned short* __restrict__ wb){
  int i = blockIdx.x*blockDim.x + threadIdx.x;
  if (i >= 9*DD*DD) return;
  int r = i >> 14; int rem = i & 16383; int n = rem >> 7; int k = rem & 127;
  float v = (r < 8) ? w[r*16384 + k*128 + n] : sw[k*128 + n];
  wb[i] = f2bf(v);
}

// ---- CSR build ------------------------------------------------------------
__global__ void k_count(const int* __restrict__ ei, const int* __restrict__ et,
                        int* __restrict__ counts){
  int e = blockIdx.x*blockDim.x + threadIdx.x;
  if (e >= EE) return;
  int s = ei[e], d = ei[EE + e], t = et[e];
  atomicAdd(&counts[d*RR + t], 1);
  atomicAdd(&counts[s*RR + t], 1);
}

__global__ void k_scan1(const int* __restrict__ counts, int* __restrict__ offs,
                        int* __restrict__ blksum){
  __shared__ int sd[256];
  int b = blockIdx.x, tid = threadIdx.x;
  int base = b*1024 + tid*4;
  int v0 = (base+0 < SS) ? counts[base+0] : 0;
  int v1 = (base+1 < SS) ? counts[base+1] : 0;
  int v2 = (base+2 < SS) ? counts[base+2] : 0;
  int v3 = (base+3 < SS) ? counts[base+3] : 0;
  int ts = v0+v1+v2+v3;
  sd[tid] = ts; __syncthreads();
  for (int o = 1; o < 256; o <<= 1){
    int t = (tid >= o) ? sd[tid-o] : 0;
    __syncthreads();
    sd[tid] += t;
    __syncthreads();
  }
  int ex = sd[tid] - ts;
  if (base+0 < SS) offs[base+0] = ex; ex += v0;
  if (base+1 < SS) offs[base+1] = ex; ex += v1;
  if (base+2 < SS) offs[base+2] = ex; ex += v2;
  if (base+3 < SS) offs[base+3] = ex;
  if (tid == 255) blksum[b] = sd[255];
}

__global__ void k_scan2(int* __restrict__ blksum, int* __restrict__ offs, int nb){
  __shared__ int sd[512];
  int tid = threadIdx.x;
  int v = (tid < nb) ? blksum[tid] : 0;
  sd[tid] = v; __syncthreads();
  for (int o = 1; o < 512; o <<= 1){
    int t = (tid >= o) ? sd[tid-o] : 0;
    __syncthreads();
    sd[tid] += t;
    __syncthreads();
  }
  if (tid < nb) blksum[tid] = sd[tid] - v;   // exclusive
  if (tid == 0) offs[SS] = TE;
}

__global__ void k_scan3(int* __restrict__ offs, const int* __restrict__ blksum,
                        int* __restrict__ cursor){
  int i = blockIdx.x*blockDim.x + threadIdx.x;
  if (i >= SS) return;
  int v = offs[i] + blksum[i >> 10];
  offs[i] = v;
  cursor[i] = v;
}

__global__ void k_scatter(const int* __restrict__ ei, const int* __restrict__ et,
                          int* __restrict__ cursor, int* __restrict__ esrc){
  int e = blockIdx.x*blockDim.x + threadIdx.x;
  if (e >= EE) return;
  int s = ei[e], d = ei[EE + e], t = et[e];
  int p = atomicAdd(&cursor[d*RR + t], 1); esrc[p] = s;
  int q = atomicAdd(&cursor[s*RR + t], 1); esrc[q] = d;
}

// ---- fused gather + degree-scale + GEMM -----------------------------------
// block = 256 (4 waves); tile = 32 dst rows x 128 out cols (small tile -> 2x grid
// -> ~6 blocks/CU resident for latency hiding).
// wave w gathers rows [w*8, w*8+8), computes out cols [w*32, w*32+32).
__global__ __launch_bounds__(256) void k_fused(
    const unsigned short* __restrict__ xb,
    const unsigned short* __restrict__ wb,
    const int* __restrict__ offs,
    const int* __restrict__ esrc,
    float* __restrict__ out)
{
  __shared__ __align__(16) unsigned short Alds[32][136];  // +8 bf16 pad -> 2-way bank alias (free)
  int tid  = threadIdx.x;
  int wave = tid >> 6, lane = tid & 63;
  int l15  = lane & 15, quad = lane >> 4;
  int rowbase = blockIdx.x * 32;

  f32x4 C[2][2];
  #pragma unroll
  for (int m = 0; m < 2; ++m){ C[m][0] = (f32x4)(0.f); C[m][1] = (f32x4)(0.f); }

  for (int rr = 0; rr < 9; ++rr){
    // B fragments for this wave's 32 output cols (straight from L2):
    // frag[j] = W_rr[k = ks*32 + quad*8 + j][n = wave*32 + nt*16 + l15]
    const unsigned short* wr = wb + rr * 16384;
    bf16x8 bfrag[2][4];
    #pragma unroll
    for (int nt = 0; nt < 2; ++nt)
      #pragma unroll
      for (int ks = 0; ks < 4; ++ks)
        bfrag[nt][ks] = *(const bf16x8*)(wr + (wave*32 + nt*16 + l15)*128 + ks*32 + quad*8);

    // --- gather: wave fills rows [wave*8, wave*8+8) of A tile ---
    // prefetch all 8 rows' CSR ranges up front (16 independent loads)
    int offv[8], cntv[8];
    if (rr < 8){
      #pragma unroll
      for (int d = 0; d < 8; ++d){
        int gd = rowbase + wave*8 + d;
        if (gd < NN){
          int s0 = gd*RR + rr;
          int o  = offs[s0];
          offv[d] = o;
          cntv[d] = offs[s0+1] - o;
        } else { offv[d] = 0; cntv[d] = 0; }
      }
    }
    #pragma unroll 1
    for (int d = 0; d < 8; ++d){
      int rowl = wave*8 + d;
      int gd = rowbase + rowl;
      float a0 = 0.f, a1 = 0.f;
      if (rr < 8){
        int off = offv[d], cnt = cntv[d];
        float b0 = 0.f, b1 = 0.f, c0 = 0.f, c1 = 0.f, d0 = 0.f, d1 = 0.f;
        int e = 0;
        // 4-wide batches: 4 independent esrc loads, then 4 independent row loads
        for (; e + 4 <= cnt; e += 4){
          int s0 = esrc[off+e+0], s1 = esrc[off+e+1];
          int s2 = esrc[off+e+2], s3 = esrc[off+e+3];
          unsigned int v0 = *(const unsigned int*)(xb + s0*DD + lane*2);
          unsigned int v1 = *(const unsigned int*)(xb + s1*DD + lane*2);
          unsigned int v2 = *(const unsigned int*)(xb + s2*DD + lane*2);
          unsigned int v3 = *(const unsigned int*)(xb + s3*DD + lane*2);
          a0 += bf2f((unsigned short)(v0 & 0xffffu)); a1 += bf2f((unsigned short)(v0 >> 16));
          b0 += bf2f((unsigned short)(v1 & 0xffffu)); b1 += bf2f((unsigned short)(v1 >> 16));
          c0 += bf2f((unsigned short)(v2 & 0xffffu)); c1 += bf2f((unsigned short)(v2 >> 16));
          d0 += bf2f((unsigned short)(v3 & 0xffffu)); d1 += bf2f((unsigned short)(v3 >> 16));
        }
        for (; e < cnt; ++e){
          int src = esrc[off + e];
          unsigned int v = *(const unsigned int*)(xb + src*DD + lane*2);
          a0 += bf2f((unsigned short)(v & 0xffffu));
          a1 += bf2f((unsigned short)(v >> 16));
        }
        a0 += b0 + c0 + d0;
        a1 += b1 + c1 + d1;
        float sc = (cnt > 0) ? (1.0f / (float)cnt) : 0.f;
        a0 *= sc; a1 *= sc;
      } else if (gd < NN){
        // self-loop pseudo-relation: A row = x_bf16[gd], scale 1
        unsigned int v = *(const unsigned int*)(xb + gd*DD + lane*2);
        a0 = bf2f((unsigned short)(v & 0xffffu));
        a1 = bf2f((unsigned short)(v >> 16));
      }
      unsigned int pk = ((unsigned int)f2bf(a1) << 16) | (unsigned int)f2bf(a0);
      *(unsigned int*)&Alds[rowl][lane*2] = pk;
    }
    __syncthreads();

    #pragma unroll
    for (int m = 0; m < 2; ++m){
      #pragma unroll
      for (int ks = 0; ks < 4; ++ks){
        bf16x8 af = *(const bf16x8*)&Alds[m*16 + l15][ks*32 + quad*8];
        C[m][0] = __builtin_amdgcn_mfma_f32_16x16x32_bf16(af, bfrag[0][ks], C[m][0], 0, 0, 0);
        C[m][1] = __builtin_amdgcn_mfma_f32_16x16x32_bf16(af, bfrag[1][ks], C[m][1], 0, 0, 0);
      }
    }
    __syncthreads();
  }

  // epilogue: C/D layout col = lane&15, row = quad*4 + reg
  #pragma unroll
  for (int m = 0; m < 2; ++m){
    #pragma unroll
    for (int nt = 0; nt < 2; ++nt){
      #pragma unroll
      for (int i = 0; i < 4; ++i){
        int row = m*16 + quad*4 + i;
        int gd  = rowbase + row;
        int col = wave*32 + nt*16 + l15;
        if (gd < NN) out[gd*DD + col] = C[m][nt][i];
      }
    }
  }
}

// ---- workspace layout (bytes) ---------------------------------------------
// counts   @ 0          : SS*4        = 1,600,000
// offs     @ 1,600,000  : (SS+1)*4    = 1,600,004 (+pad)
// cursor   @ 3,200,016  : SS*4        = 1,600,000
// blksum   @ 4,800,016  : 512*4       = 2,048
// esrc     @ 4,802,064  : TE*4        = 6,400,000
// xb       @ 11,202,064 : NN*DD*2     = 12,800,000
// wb       @ 24,002,064 : 9*DD*DD*2   = 294,912
// total ~ 24.30 MB
extern "C" void kernel_launch(void* const* d_in, const int* in_sizes, int n_in,
                              void* d_out, int out_size, void* d_ws, size_t ws_size,
                              hipStream_t stream){
  const float* x  = (const float*)d_in[0];
  const float* w  = (const float*)d_in[1];
  const float* sw = (const float*)d_in[2];
  const int*   ei = (const int*)d_in[3];
  const int*   et = (const int*)d_in[4];
  float* out = (float*)d_out;
  char* ws = (char*)d_ws;

  if (ws_size < (size_t)24300000) return;

  int* counts = (int*)(ws + 0);
  int* offs   = (int*)(ws + 1600000);
  int* cursor = (int*)(ws + 3200016);
  int* blksum = (int*)(ws + 4800016);
  int* esrc   = (int*)(ws + 4802064);
  unsigned short* xb = (unsigned short*)(ws + 11202064);
  unsigned short* wb = (unsigned short*)(ws + 24002064);

  hipMemsetAsync(counts, 0, SS*sizeof(int), stream);
  k_conv_x <<<(NN*DD/4 + 255)/256, 256, 0, stream>>>(x, xb);
  k_conv_w <<<(9*DD*DD + 255)/256, 256, 0, stream>>>(w, sw, wb);
  k_count  <<<(EE + 255)/256,      256, 0, stream>>>(ei, et, counts);
  k_scan1  <<<391,                 256, 0, stream>>>(counts, offs, blksum);
  k_scan2  <<<1,                   512, 0, stream>>>(blksum, offs, 391);
  k_scan3  <<<(SS + 255)/256,      256, 0, stream>>>(offs, blksum, cursor);
  k_scatter<<<(EE + 255)/256,      256, 0, stream>>>(ei, et, cursor, esrc);
  k_fused  <<<(NN + 31)/32,        256, 0, stream>>>(xb, wb, offs, esrc, out);
}

// Round 3
// 413.301 us; speedup vs baseline: 1.6457x; 1.4000x over previous
//
#include <hip/hip_runtime.h>

#define NN 50000
#define EE 800000
#define RR 8
#define DD 128
#define SS (NN*RR)      // 400000 segments
#define TE (2*EE)       // 1600000 symmetrized edges

typedef __attribute__((ext_vector_type(8))) short bf16x8;
typedef __attribute__((ext_vector_type(4))) float f32x4;

__device__ __forceinline__ unsigned short f2bf(float f){
  unsigned int u = __float_as_uint(f);
  u += 0x7fffu + ((u >> 16) & 1u);   // round-to-nearest-even
  return (unsigned short)(u >> 16);
}
__device__ __forceinline__ float bf_lo(unsigned int w){ return __uint_as_float(w << 16); }
__device__ __forceinline__ float bf_hi(unsigned int w){ return __uint_as_float(w & 0xffff0000u); }

__device__ __forceinline__ void acc8(float* a, uint4 u){
  a[0] += bf_lo(u.x); a[1] += bf_hi(u.x);
  a[2] += bf_lo(u.y); a[3] += bf_hi(u.y);
  a[4] += bf_lo(u.z); a[5] += bf_hi(u.z);
  a[6] += bf_lo(u.w); a[7] += bf_hi(u.w);
}
__device__ __forceinline__ unsigned int pack2(float a, float b){
  return ((unsigned int)f2bf(b) << 16) | (unsigned int)f2bf(a);
}

// ---- prep: x fp32 -> bf16 -------------------------------------------------
__global__ void k_conv_x(const float* __restrict__ x, unsigned short* __restrict__ xb){
  int i = blockIdx.x*blockDim.x + threadIdx.x;
  if (i >= NN*DD/4) return;
  float4 v = ((const float4*)x)[i];
  ushort4 o;
  o.x = f2bf(v.x); o.y = f2bf(v.y); o.z = f2bf(v.z); o.w = f2bf(v.w);
  ((ushort4*)xb)[i] = o;
}

// ---- prep: W[r][k][n] fp32 -> wb[r][n][k] bf16 (B-fragment layout), r=8 is self_weight
__global__ void k_conv_w(const float* __restrict__ w, const float* __restrict__ sw,
                         unsigned short* __restrict__ wb){
  int i = blockIdx.x*blockDim.x + threadIdx.x;
  if (i >= 9*DD*DD) return;
  int r = i >> 14; int rem = i & 16383; int n = rem >> 7; int k = rem & 127;
  float v = (r < 8) ? w[r*16384 + k*128 + n] : sw[k*128 + n];
  wb[i] = f2bf(v);
}

// ---- CSR build ------------------------------------------------------------
__global__ void k_count(const int* __restrict__ ei, const int* __restrict__ et,
                        int* __restrict__ counts){
  int e = blockIdx.x*blockDim.x + threadIdx.x;
  if (e >= EE) return;
  int s = ei[e], d = ei[EE + e], t = et[e];
  atomicAdd(&counts[d*RR + t], 1);
  atomicAdd(&counts[s*RR + t], 1);
}

__global__ void k_scan1(const int* __restrict__ counts, int* __restrict__ offs,
                        int* __restrict__ blksum){
  __shared__ int sd[256];
  int b = blockIdx.x, tid = threadIdx.x;
  int base = b*1024 + tid*4;
  int v0 = (base+0 < SS) ? counts[base+0] : 0;
  int v1 = (base+1 < SS) ? counts[base+1] : 0;
  int v2 = (base+2 < SS) ? counts[base+2] : 0;
  int v3 = (base+3 < SS) ? counts[base+3] : 0;
  int ts = v0+v1+v2+v3;
  sd[tid] = ts; __syncthreads();
  for (int o = 1; o < 256; o <<= 1){
    int t = (tid >= o) ? sd[tid-o] : 0;
    __syncthreads();
    sd[tid] += t;
    __syncthreads();
  }
  int ex = sd[tid] - ts;
  if (base+0 < SS) offs[base+0] = ex; ex += v0;
  if (base+1 < SS) offs[base+1] = ex; ex += v1;
  if (base+2 < SS) offs[base+2] = ex; ex += v2;
  if (base+3 < SS) offs[base+3] = ex;
  if (tid == 255) blksum[b] = sd[255];
}

__global__ void k_scan2(int* __restrict__ blksum, int* __restrict__ offs, int nb){
  __shared__ int sd[512];
  int tid = threadIdx.x;
  int v = (tid < nb) ? blksum[tid] : 0;
  sd[tid] = v; __syncthreads();
  for (int o = 1; o < 512; o <<= 1){
    int t = (tid >= o) ? sd[tid-o] : 0;
    __syncthreads();
    sd[tid] += t;
    __syncthreads();
  }
  if (tid < nb) blksum[tid] = sd[tid] - v;   // exclusive
  if (tid == 0) offs[SS] = TE;
}

__global__ void k_scan3(int* __restrict__ offs, const int* __restrict__ blksum,
                        int* __restrict__ cursor){
  int i = blockIdx.x*blockDim.x + threadIdx.x;
  if (i >= SS) return;
  int v = offs[i] + blksum[i >> 10];
  offs[i] = v;
  cursor[i] = v;
}

__global__ void k_scatter(const int* __restrict__ ei, const int* __restrict__ et,
                          int* __restrict__ cursor, int* __restrict__ esrc){
  int e = blockIdx.x*blockDim.x + threadIdx.x;
  if (e >= EE) return;
  int s = ei[e], d = ei[EE + e], t = et[e];
  int p = atomicAdd(&cursor[d*RR + t], 1); esrc[p] = s;
  int q = atomicAdd(&cursor[s*RR + t], 1); esrc[q] = d;
}

// ---- fused gather + degree-scale + GEMM -----------------------------------
// block = 256 (4 waves); tile = 32 dst rows x 128 out cols.
// Gather is GROUP-parallel: each wave = 4 groups of 16 lanes; a group owns a
// full 128-dim row via dwordx4 (16B/lane) loads; edge srcs are loaded
// cooperatively (16 at once) and broadcast by __shfl. Up to 16 row-loads in
// flight per wave. LDS is double-buffered: gather(rr+1) overlaps MFMA(rr),
// one barrier per relation.
__global__ __launch_bounds__(256) void k_fused(
    const unsigned short* __restrict__ xb,
    const unsigned short* __restrict__ wb,
    const int* __restrict__ offs,
    const int* __restrict__ esrc,
    float* __restrict__ out)
{
  __shared__ __align__(16) unsigned short Alds[2][32][136]; // +8 pad: 2-way bank alias (free)
  const int tid  = threadIdx.x;
  const int wave = tid >> 6, lane = tid & 63;
  const int l15  = lane & 15, quad = lane >> 4;
  const int g    = quad;          // 16-lane group id within wave
  const int gl   = l15;           // lane within group
  const int gbase = g << 4;       // wave-lane index of group's lane 0
  const int rowbase = blockIdx.x * 32;

  f32x4 C[2][2];
  #pragma unroll
  for (int m = 0; m < 2; ++m){ C[m][0] = (f32x4)(0.f); C[m][1] = (f32x4)(0.f); }

  auto gather = [&](int rr, int b){
    // prefetch CSR ranges for this wave's 8 rows: lanes 0..15 hold
    // offs[gd*8+rr] (even lanes) / offs[gd*8+rr+1] (odd lanes)
    int v = 0;
    if (rr < 8 && lane < 16){
      int gdj = rowbase + wave*8 + (lane >> 1);
      if (gdj < NN) v = offs[gdj*8 + rr + (lane & 1)];
    }
    #pragma unroll
    for (int p = 0; p < 2; ++p){
      int rl8  = 2*g + p;            // row within wave's 8
      int rowl = wave*8 + rl8;       // row within 32-row tile
      int gd   = rowbase + rowl;
      uint4 u = make_uint4(0u,0u,0u,0u);
      if (rr == 8){
        if (gd < NN) u = *(const uint4*)(xb + (size_t)gd*DD + gl*8);
      } else {
        int off = __shfl(v, 2*rl8);
        int end = __shfl(v, 2*rl8 + 1);
        int cnt = (gd < NN) ? (end - off) : 0;
        float a[8] = {0.f,0.f,0.f,0.f,0.f,0.f,0.f,0.f};
        int idxv = 0;
        if (gl < cnt) idxv = esrc[off + gl];     // first up-to-16 srcs, coalesced
        int cm = cnt < 16 ? cnt : 16;
        int e = 0;
        for (; e + 4 <= cm; e += 4){
          int s0 = __shfl(idxv, gbase + e + 0);
          int s1 = __shfl(idxv, gbase + e + 1);
          int s2 = __shfl(idxv, gbase + e + 2);
          int s3 = __shfl(idxv, gbase + e + 3);
          uint4 u0 = *(const uint4*)(xb + (size_t)s0*DD + gl*8);
          uint4 u1 = *(const uint4*)(xb + (size_t)s1*DD + gl*8);
          uint4 u2 = *(const uint4*)(xb + (size_t)s2*DD + gl*8);
          uint4 u3 = *(const uint4*)(xb + (size_t)s3*DD + gl*8);
          acc8(a, u0); acc8(a, u1); acc8(a, u2); acc8(a, u3);
        }
        for (; e < cm; ++e){
          int s0 = __shfl(idxv, gbase + e);
          uint4 u0 = *(const uint4*)(xb + (size_t)s0*DD + gl*8);
          acc8(a, u0);
        }
        for (int e2 = 16; e2 < cnt; ++e2){       // rare Poisson tail (cnt>16)
          int s0 = esrc[off + e2];
          uint4 u0 = *(const uint4*)(xb + (size_t)s0*DD + gl*8);
          acc8(a, u0);
        }
        float sc = (cnt > 0) ? (1.0f / (float)cnt) : 0.f;
        u.x = pack2(a[0]*sc, a[1]*sc);
        u.y = pack2(a[2]*sc, a[3]*sc);
        u.z = pack2(a[4]*sc, a[5]*sc);
        u.w = pack2(a[6]*sc, a[7]*sc);
      }
      *(uint4*)&Alds[b][rowl][gl*8] = u;
    }
  };

  gather(0, 0);
  __syncthreads();

  #pragma unroll 1
  for (int rr = 0; rr < 9; ++rr){
    int b = rr & 1;
    if (rr < 8) gather(rr + 1, b ^ 1);   // overlaps MFMA phase below

    // B fragments: frag[j] = W_rr[k = ks*32 + quad*8 + j][n = wave*32 + nt*16 + l15]
    const unsigned short* wr = wb + rr * 16384;
    bf16x8 bfrag[2][4];
    #pragma unroll
    for (int nt = 0; nt < 2; ++nt)
      #pragma unroll
      for (int ks = 0; ks < 4; ++ks)
        bfrag[nt][ks] = *(const bf16x8*)(wr + (wave*32 + nt*16 + l15)*128 + ks*32 + quad*8);

    #pragma unroll
    for (int m = 0; m < 2; ++m){
      #pragma unroll
      for (int ks = 0; ks < 4; ++ks){
        bf16x8 af = *(const bf16x8*)&Alds[b][m*16 + l15][ks*32 + quad*8];
        C[m][0] = __builtin_amdgcn_mfma_f32_16x16x32_bf16(af, bfrag[0][ks], C[m][0], 0, 0, 0);
        C[m][1] = __builtin_amdgcn_mfma_f32_16x16x32_bf16(af, bfrag[1][ks], C[m][1], 0, 0, 0);
      }
    }
    __syncthreads();
  }

  // epilogue: C/D layout col = lane&15, row = quad*4 + reg
  #pragma unroll
  for (int m = 0; m < 2; ++m){
    #pragma unroll
    for (int nt = 0; nt < 2; ++nt){
      #pragma unroll
      for (int i = 0; i < 4; ++i){
        int row = m*16 + quad*4 + i;
        int gd  = rowbase + row;
        int col = wave*32 + nt*16 + l15;
        if (gd < NN) out[gd*DD + col] = C[m][nt][i];
      }
    }
  }
}

// ---- workspace layout (bytes) ---------------------------------------------
// counts   @ 0          : SS*4        = 1,600,000
// offs     @ 1,600,000  : (SS+1)*4    = 1,600,004 (+pad)
// cursor   @ 3,200,016  : SS*4        = 1,600,000
// blksum   @ 4,800,016  : 512*4       = 2,048
// esrc     @ 4,802,064  : TE*4        = 6,400,000
// xb       @ 11,202,064 : NN*DD*2     = 12,800,000
// wb       @ 24,002,064 : 9*DD*DD*2   = 294,912
// total ~ 24.30 MB
extern "C" void kernel_launch(void* const* d_in, const int* in_sizes, int n_in,
                              void* d_out, int out_size, void* d_ws, size_t ws_size,
                              hipStream_t stream){
  const float* x  = (const float*)d_in[0];
  const float* w  = (const float*)d_in[1];
  const float* sw = (const float*)d_in[2];
  const int*   ei = (const int*)d_in[3];
  const int*   et = (const int*)d_in[4];
  float* out = (float*)d_out;
  char* ws = (char*)d_ws;

  if (ws_size < (size_t)24300000) return;

  int* counts = (int*)(ws + 0);
  int* offs   = (int*)(ws + 1600000);
  int* cursor = (int*)(ws + 3200016);
  int* blksum = (int*)(ws + 4800016);
  int* esrc   = (int*)(ws + 4802064);
  unsigned short* xb = (unsigned short*)(ws + 11202064);
  unsigned short* wb = (unsigned short*)(ws + 24002064);

  hipMemsetAsync(counts, 0, SS*sizeof(int), stream);
  k_conv_x <<<(NN*DD/4 + 255)/256, 256, 0, stream>>>(x, xb);
  k_conv_w <<<(9*DD*DD + 255)/256, 256, 0, stream>>>(w, sw, wb);
  k_count  <<<(EE + 255)/256,      256, 0, stream>>>(ei, et, counts);
  k_scan1  <<<391,                 256, 0, stream>>>(counts, offs, blksum);
  k_scan2  <<<1,                   512, 0, stream>>>(blksum, offs, 391);
  k_scan3  <<<(SS + 255)/256,      256, 0, stream>>>(offs, blksum, cursor);
  k_scatter<<<(EE + 255)/256,      256, 0, stream>>>(ei, et, cursor, esrc);
  k_fused  <<<(NN + 31)/32,        256, 0, stream>>>(xb, wb, offs, esrc, out);
}